// Round 5
// baseline (152.349 us; speedup 1.0000x reference)
//
#include <hip/hip_runtime.h>

#define NEMB 64   // K = NUM_BINS + 1
#define DIM  64   // EMB_DIM
#define NBINS 63

typedef float f32x4 __attribute__((ext_vector_type(4)));

// T[i][d] = sum_k weight[k][d] / (|i-k|+1)   (16 KB table in d_ws)
__global__ __launch_bounds__(256) void build_table_kernel(
    const float* __restrict__ weight, float* __restrict__ T) {
    const int e = blockIdx.x * 256 + threadIdx.x;  // 0..4095
    const int i = e >> 6;   // table row
    const int d = e & 63;   // dim
    float acc = 0.0f;
    #pragma unroll
    for (int k = 0; k < NEMB; ++k) {
        int diff = i - k;
        diff = diff < 0 ? -diff : diff;
        acc += weight[k * DIM + d] * (1.0f / (float)(diff + 1));
    }
    T[e] = acc;
}

// Barrier-free gather: each wave autonomously owns 64 consecutive rows.
// Per wave: coalesced x load -> exact binary-search bucketize (per-wave LDS
// bins, wave-synchronous) -> idx exchange via wave-local LDS broadcast reads
// -> 16 iterations of {L1-hit table row load, contiguous 1 KB nt store}.
__global__ __launch_bounds__(256) void emb_gather_kernel(
    const float* __restrict__ x,
    const float* __restrict__ low,
    const f32x4* __restrict__ T4,
    f32x4* __restrict__ out4,
    int n_rows) {
    // Per-wave private LDS (wave-synchronous access, no __syncthreads):
    __shared__ float bins_lds[4][NBINS];
    __shared__ int   idx_lds[4][64];

    const int t    = threadIdx.x;
    const int w    = t >> 6;          // wave id 0..3
    const int l    = t & 63;          // lane id
    const int wbase = blockIdx.x * 256 + w * 64;   // wave's first row

    // Stage bins into this wave's LDS copy (lanes 0..62).
    if (l < NBINS) bins_lds[w][l] = low[l + 1];
    // (wave-synchronous: compiler inserts lgkmcnt before dependent reads)

    // Phase 1: lane l computes bucket index for row wbase+l.
    // index = #{ j : x > bins[j] } via branchless binary search
    // (strides 32+16+8+4+2+1 = 63; probes provably stay in [0,62]).
    {
        const int row = wbase + l;
        float xv = (row < n_rows) ? x[row] : 0.0f;
        int c = 0;
        if (xv > bins_lds[w][c + 31]) c += 32;
        if (xv > bins_lds[w][c + 15]) c += 16;
        if (xv > bins_lds[w][c + 7])  c += 8;
        if (xv > bins_lds[w][c + 3])  c += 4;
        if (xv > bins_lds[w][c + 1])  c += 2;
        if (xv > bins_lds[w][c])      c += 1;
        idx_lds[w][l] = c;
    }

    // Phase 2: per iteration the wave writes 4 rows = 1 KB contiguous.
    const int sub   = l >> 4;   // row-in-group 0..3
    const int lane4 = l & 15;   // float4 slot within the 64-float row
    #pragma unroll
    for (int it = 0; it < 16; ++it) {
        const int r    = it * 4 + sub;        // row within wave chunk (0..63)
        const int grow = wbase + r;
        if (grow < n_rows) {
            const int idx = idx_lds[w][r];    // broadcast read, conflict-free
            const f32x4 v = T4[idx * 16 + lane4];   // L1-resident table row
            __builtin_nontemporal_store(v, &out4[grow * 16 + lane4]);
        }
    }
}

extern "C" void kernel_launch(void* const* d_in, const int* in_sizes, int n_in,
                              void* d_out, int out_size, void* d_ws, size_t ws_size,
                              hipStream_t stream) {
    const float* x      = (const float*)d_in[0];   // [B*F]
    const float* low    = (const float*)d_in[1];   // [64]  (-inf, bins...)
    const float* weight = (const float*)d_in[3];   // [64*64]
    float* out = (float*)d_out;
    float* T   = (float*)d_ws;                     // 16 KB table scratch

    const int n_rows = in_sizes[0];                // B*F = 524288

    build_table_kernel<<<16, 256, 0, stream>>>(weight, T);

    const int blocks = (n_rows + 255) / 256;       // 2048
    emb_gather_kernel<<<blocks, 256, 0, stream>>>(
        x, low, (const f32x4*)T, (f32x4*)out, n_rows);
}